// Round 5
// baseline (2962.939 us; speedup 1.0000x reference)
//
#include <hip/hip_runtime.h>
#include <hip/hip_bf16.h>
#include <hip/hip_cooperative_groups.h>

namespace cg = cooperative_groups;

// Problem constants (fixed by setup_inputs)
#define BATCH 512
#define HDIM  1024
#define G4    4096   // 4*H
#define DSTEP 64
#define NOUT  512
#define HB    ((size_t)BATCH * HDIM)

typedef __bf16 bf16;
typedef __bf16 bf16x8 __attribute__((ext_vector_type(8)));
typedef float  f32x4  __attribute__((ext_vector_type(4)));

#define MFMA16(a, b, c) __builtin_amdgcn_mfma_f32_16x16x32_bf16((a), (b), (c), 0, 0, 0)

#define GLOAD_LDS16(g, l)                                                           \
    __builtin_amdgcn_global_load_lds((const __attribute__((address_space(1))) void*)(g), \
                                     (__attribute__((address_space(3))) void*)(l), 16, 0, 0)

__device__ __forceinline__ float sigmoid_f(float x) { return 1.0f / (1.0f + __expf(-x)); }
__device__ __forceinline__ float tanh_f(float x)    { return 1.0f - 2.0f / (__expf(2.0f * x) + 1.0f); }

// segment swizzle for [row][32] bf16 LDS tiles (4 segments of 16B per 64B row)
__device__ __forceinline__ int swz4(int row) { return (row ^ (row >> 2)) & 3; }

// ---------------- prep: fp32 -> bf16 conversions + layout transforms ----------------
// Whh is written GATE-INTERLEAVED: row' = hcol*4 + gate  (so a 128-gatecol tile = 32 hcols x 4 gates)
__global__ void prep_kernel(const float* __restrict__ x, const float* __restrict__ h0,
                            const float* __restrict__ W_ih, const float* __restrict__ W_hh,
                            const float* __restrict__ W_out,
                            bf16* __restrict__ x_b, bf16* __restrict__ Wih_b,
                            bf16* __restrict__ Whh_i, bf16* __restrict__ Wout_b,
                            bf16* __restrict__ h_slot0) {
    int tid = blockIdx.x * blockDim.x + threadIdx.x;
    int stride = gridDim.x * blockDim.x;
    for (int i = tid; i < G4 * HDIM; i += stride) {
        int r = i >> 10, k = i & 1023;
        int r2 = ((r & 1023) << 2) | (r >> 10);   // interleave: hcol*4 + gate
        Whh_i[(size_t)r2 * HDIM + k] = (bf16)W_hh[i];
        Wih_b[i] = (bf16)W_ih[i];
    }
    for (int i = tid; i < BATCH * HDIM; i += stride) {
        x_b[i]     = (bf16)x[i];
        Wout_b[i]  = (bf16)W_out[i];
        h_slot0[i] = (bf16)h0[i];
    }
}

// ---------------- tiled C = A @ B^T + bias(+bias2) (bf16 in, f32 out) ----------------
// 128x128 tile, BK=32, double-buffered LDS via global_load_lds(16B), 4 waves (64x64 each).
// INTER: store columns gate-interleaved (col' = (col&1023)*4 + col>>10).
template <int M, int N, int K, bool INTER>
__global__ __launch_bounds__(256) void gemm_bt_tiled(const bf16* __restrict__ A,
                                                     const bf16* __restrict__ Bw,
                                                     const float* __restrict__ bias,
                                                     const float* __restrict__ bias2,
                                                     float* __restrict__ C) {
    constexpr int MT = M / 128;
    constexpr int NT = N / 128;
    constexpr int TOT = MT * NT;
    __shared__ bf16 sA[2][128 * 32];
    __shared__ bf16 sB[2][128 * 32];

    int bid = blockIdx.x;
    int g = (bid & 7) * (TOT / 8) + (bid >> 3);  // XCD-chunked
    int nt = g % NT, mt = g / NT;
    int mrow0 = mt * 128, ncol0 = nt * 128;

    int tid = threadIdx.x;
    int l = tid & 63;
    int w = tid >> 6;
    int wr = w >> 1, wc = w & 1;
    int lr = l & 15, q = l >> 4;

    const bf16* Abase = A + (size_t)mrow0 * K;
    const bf16* Bbase = Bw + (size_t)ncol0 * K;

    auto stage = [&](const bf16* base, bf16* dst, int k0) {
#pragma unroll
        for (int j = 0; j < 2; ++j) {
            int pbase = w * 64 + 256 * j;
            int p = pbase + l;
            int row = p >> 2, seg = p & 3;
            int sseg = seg ^ swz4(row);
            const bf16* gp = base + (size_t)row * K + k0 + sseg * 8;
            GLOAD_LDS16(gp, dst + pbase * 8);
        }
    };

    stage(Abase, sA[0], 0);
    stage(Bbase, sB[0], 0);
    __syncthreads();

    f32x4 acc[4][4] = {};
    constexpr int NS = K / 32;
    for (int s = 0; s < NS; ++s) {
        int cur = s & 1;
        if (s + 1 < NS) {
            stage(Abase, sA[cur ^ 1], (s + 1) * 32);
            stage(Bbase, sB[cur ^ 1], (s + 1) * 32);
        }
        bf16x8 af[4], bf[4];
#pragma unroll
        for (int fm = 0; fm < 4; ++fm) {
            int row = wr * 64 + fm * 16 + lr;
            af[fm] = *(const bf16x8*)&sA[cur][row * 32 + 8 * (q ^ swz4(row))];
        }
#pragma unroll
        for (int fn = 0; fn < 4; ++fn) {
            int row = wc * 64 + fn * 16 + lr;
            bf[fn] = *(const bf16x8*)&sB[cur][row * 32 + 8 * (q ^ swz4(row))];
        }
#pragma unroll
        for (int fm = 0; fm < 4; ++fm)
#pragma unroll
            for (int fn = 0; fn < 4; ++fn)
                acc[fm][fn] = MFMA16(af[fm], bf[fn], acc[fm][fn]);
        __syncthreads();
    }

#pragma unroll
    for (int fm = 0; fm < 4; ++fm)
#pragma unroll
        for (int fn = 0; fn < 4; ++fn) {
            int col = ncol0 + wc * 64 + fn * 16 + lr;
            float bs = bias[col] + (bias2 ? bias2[col] : 0.0f);
            int colw = INTER ? (((col & 1023) << 2) | (col >> 10)) : col;
#pragma unroll
            for (int r = 0; r < 4; ++r) {
                int row = mrow0 + wr * 64 + fm * 16 + q * 4 + r;
                C[(size_t)row * N + colw] = acc[fm][fn][r] + bs;
            }
        }
}

// ---------------- persistent LSTM scan (cooperative) ----------------
// 256 blocks x 512 threads, 1 block/CU. Block tile: 64 batch rows x 128 gatecols (32 hcols).
// Whh panel lives in REGISTERS (128 VGPR/lane, loaded once). xW slice + bias in regs (16).
// c slice in regs (4, block-private). Per step: stage h panel (128KB LDS, swizzled),
// MFMA (K-split across wave pairs), LDS reduce + gate combine, elementwise update,
// write h[t+1], grid sync.
__global__ __launch_bounds__(512, 2) void persistent_lstm(
    const bf16* __restrict__ Whh_i,   // [4096][1024], rows gate-interleaved
    const float* __restrict__ xWi,    // [512][4096], cols gate-interleaved, biases folded in
    const float* __restrict__ c0,     // [512][1024] f32
    bf16* __restrict__ h_all)         // [65][512][1024] bf16
{
    __shared__ __align__(16) char smem[131072];      // 128 KB
    bf16*  A_lds = (bf16*)smem;                      // [64][1024] h panel (swizzled)
    float* red   = (float*)smem;                     // 32 KB alias (post-MFMA)
    float* gbuf  = (float*)(smem + 32768);           // 32 KB alias (post-MFMA)

    int bid = blockIdx.x;
    int mb = bid & 7;        // batch group == XCD (round-robin dispatch)
    int nb = bid >> 3;       // gatecol group 0..31

    int tid = threadIdx.x;
    int l   = tid & 63;
    int wid = tid >> 6;      // 8 waves
    int nt4 = wid & 3;       // col sub-tile (32 gatecols each)
    int kw  = wid >> 2;      // K-split half
    int lr = l & 15, q = l >> 4;

    int row0 = mb * 64;
    int gc0  = nb * 128 + nt4 * 32;

    // ---- B stash: 32 gatecols x 512 K in regs (16 kc x 2 fn x bf16x8 = 128 VGPR) ----
    bf16x8 Breg[16][2];
#pragma unroll
    for (int kc = 0; kc < 16; ++kc)
#pragma unroll
        for (int fn = 0; fn < 2; ++fn)
            Breg[kc][fn] = *(const bf16x8*)&Whh_i[(size_t)(gc0 + fn * 16 + lr) * HDIM +
                                                  kw * 512 + kc * 32 + q * 8];

    // ---- xW (+biases) stash and c stash: elementwise mapping, 4 (row,hcol)/thread ----
    float4 xws[4];
    float  cst[4];
#pragma unroll
    for (int it = 0; it < 4; ++it) {
        int idx = it * 512 + tid;
        int row = idx >> 5, hl = idx & 31;
        int grow = row0 + row;
        int hcol = nb * 32 + hl;
        xws[it] = *(const float4*)&xWi[(size_t)grow * G4 + (size_t)hcol * 4];
        cst[it] = c0[(size_t)grow * HDIM + hcol];
    }

    cg::grid_group grid = cg::this_grid();

    for (int t = 0; t < DSTEP; ++t) {
        // ---- stage h[t] panel: 64 rows x 1024, XOR-swizzled segs (seg ^= row&7) ----
        const bf16* hsrc = h_all + (size_t)t * HB + (size_t)row0 * HDIM;
#pragma unroll
        for (int jj = 0; jj < 16; ++jj) {
            int base = jj * 512 + wid * 64;      // wave-uniform 16B-slot base
            int p = base + l;
            int rown = p >> 7, ss = p & 127;
            int sg = ss ^ (rown & 7);            // inverse swizzle on SOURCE (rule #21)
            GLOAD_LDS16(hsrc + (size_t)rown * HDIM + sg * 8, A_lds + (size_t)base * 8);
        }
        __syncthreads();                         // compiler drains vmcnt before barrier

        // ---- MFMA: wave computes 64 rows x 32 cols over its K-half ----
        f32x4 acc[4][2] = {};
#pragma unroll
        for (int kc = 0; kc < 16; ++kc) {
            bf16x8 af[4];
#pragma unroll
            for (int fm = 0; fm < 4; ++fm) {
                int rown = fm * 16 + lr;
                int seg = kw * 64 + kc * 4 + q;
                af[fm] = *(const bf16x8*)&A_lds[(size_t)(rown * 128 + (seg ^ (lr & 7))) * 8];
            }
#pragma unroll
            for (int fm = 0; fm < 4; ++fm) {
                acc[fm][0] = MFMA16(af[fm], Breg[kc][0], acc[fm][0]);
                acc[fm][1] = MFMA16(af[fm], Breg[kc][1], acc[fm][1]);
            }
        }
        __syncthreads();   // all waves done reading A before aliasing red/gbuf onto it

        // ---- K-split reduce (register-exact map) + gate tile to LDS ----
        if (kw == 1) {
#pragma unroll
            for (int fm = 0; fm < 4; ++fm)
#pragma unroll
                for (int fn = 0; fn < 2; ++fn)
#pragma unroll
                    for (int r = 0; r < 4; ++r)
                        red[(((nt4 * 4 + fm) * 2 + fn) * 4 + r) * 64 + l] = acc[fm][fn][r];
        }
        __syncthreads();
        if (kw == 0) {
#pragma unroll
            for (int fm = 0; fm < 4; ++fm)
#pragma unroll
                for (int fn = 0; fn < 2; ++fn) {
                    int col = nt4 * 32 + fn * 16 + lr;
#pragma unroll
                    for (int r = 0; r < 4; ++r) {
                        float v = acc[fm][fn][r] +
                                  red[(((nt4 * 4 + fm) * 2 + fn) * 4 + r) * 64 + l];
                        gbuf[(fm * 16 + q * 4 + r) * 128 + col] = v;   // C/D: col=lane&15
                    }
                }
        }
        __syncthreads();

        // ---- fused LSTM elementwise: 64 rows x 32 hcols, gates adjacent (float4) ----
        bf16* hdst = h_all + (size_t)(t + 1) * HB;
#pragma unroll
        for (int it = 0; it < 4; ++it) {
            int idx = it * 512 + tid;
            int row = idx >> 5, hl = idx & 31;
            float4 g4 = *(const float4*)&gbuf[row * 128 + hl * 4];
            float gi = g4.x + xws[it].x;
            float gf = g4.y + xws[it].y;
            float gg = g4.z + xws[it].z;
            float go = g4.w + xws[it].w;
            float cn = sigmoid_f(gf) * cst[it] + sigmoid_f(gi) * tanh_f(gg);
            float hn = sigmoid_f(go) * tanh_f(cn);
            cst[it] = cn;
            hdst[(size_t)(row0 + row) * HDIM + nb * 32 + hl] = (bf16)hn;
        }
        if (t + 1 < DSTEP) grid.sync();   // release h[t+1] to all XCDs
    }
}

// ---------------- launch ----------------
extern "C" void kernel_launch(void* const* d_in, const int* in_sizes, int n_in,
                              void* d_out, int out_size, void* d_ws, size_t ws_size,
                              hipStream_t stream) {
    const float* x    = (const float*)d_in[0];
    const float* h0   = (const float*)d_in[1];
    const float* c0   = (const float*)d_in[2];
    const float* W_ih = (const float*)d_in[3];
    const float* W_hh = (const float*)d_in[4];
    const float* b_ih = (const float*)d_in[5];
    const float* b_hh = (const float*)d_in[6];
    const float* W_out= (const float*)d_in[7];
    const float* b_out= (const float*)d_in[8];

    char* ws = (char*)d_ws;
    bf16*  Whh_i  = (bf16*)(ws + 0);                     // 8 MB (gate-interleaved)
    bf16*  Wih_b  = (bf16*)(ws + (size_t)(8 << 20));     // 8 MB
    bf16*  x_b    = (bf16*)(ws + (size_t)(16 << 20));    // 1 MB
    bf16*  Wout_b = (bf16*)(ws + (size_t)(17 << 20));    // 1 MB
    float* xWbuf  = (float*)(ws + (size_t)(18 << 20));   // 8 MB (interleaved cols, biases folded)
    bf16*  h_all  = (bf16*)(ws + (size_t)(28 << 20));    // 65 MB (65 slots of 512x1024)

    prep_kernel<<<2048, 256, 0, stream>>>(x, h0, W_ih, W_hh, W_out,
                                          x_b, Wih_b, Whh_i, Wout_b, h_all);

    // xWi = x @ W_ih^T + b_ih + b_hh, stored gate-interleaved: M=512, N=4096 -> 128 blocks
    gemm_bt_tiled<BATCH, G4, HDIM, true><<<128, 256, 0, stream>>>(x_b, Wih_b, b_ih, b_hh, xWbuf);

    // all 64 LSTM steps in one cooperative persistent kernel
    {
        const bf16*  whh_arg  = Whh_i;
        const float* xwi_arg  = xWbuf;
        const float* c0_arg   = c0;
        bf16*        hall_arg = h_all;
        void* kargs[] = {(void*)&whh_arg, (void*)&xwi_arg, (void*)&c0_arg, (void*)&hall_arg};
        hipLaunchCooperativeKernel((const void*)persistent_lstm, dim3(256), dim3(512),
                                   kargs, 0, stream);
    }

    // outs = h_all[1..64] @ W_out^T + b_out : M=32768, N=512 -> 1024 blocks
    gemm_bt_tiled<DSTEP * BATCH, NOUT, HDIM, false><<<1024, 256, 0, stream>>>(
        h_all + HB, Wout_b, b_out, nullptr, (float*)d_out);
}

// Round 7
// 1220.227 us; speedup vs baseline: 2.4282x; 2.4282x over previous
//
#include <hip/hip_runtime.h>
#include <hip/hip_bf16.h>

// Problem constants (fixed by setup_inputs)
#define BATCH 512
#define HDIM  1024
#define G4    4096   // 4*H
#define DSTEP 64
#define NOUT  512
#define HB    ((size_t)BATCH * HDIM)

typedef __bf16 bf16;
typedef __bf16 bf16x8 __attribute__((ext_vector_type(8)));
typedef float  f32x4  __attribute__((ext_vector_type(4)));

#define MFMA16(a, b, c) __builtin_amdgcn_mfma_f32_16x16x32_bf16((a), (b), (c), 0, 0, 0)

#define GLOAD_LDS16(g, l)                                                           \
    __builtin_amdgcn_global_load_lds((const __attribute__((address_space(1))) void*)(g), \
                                     (__attribute__((address_space(3))) void*)(l), 16, 0, 0)

__device__ __forceinline__ float sigmoid_f(float x) { return 1.0f / (1.0f + __expf(-x)); }
__device__ __forceinline__ float tanh_f(float x)    { return 1.0f - 2.0f / (__expf(2.0f * x) + 1.0f); }

// segment swizzle for [row][32] bf16 LDS tiles (4 segments of 16B per 64B row)
__device__ __forceinline__ int swz4(int row) { return (row ^ (row >> 2)) & 3; }

// ---------------- prep: fp32 -> bf16 conversions + layout transforms ----------------
// Whh is written GATE-INTERLEAVED: row' = hcol*4 + gate
__global__ void prep_kernel(const float* __restrict__ x, const float* __restrict__ h0,
                            const float* __restrict__ c0,
                            const float* __restrict__ W_ih, const float* __restrict__ W_hh,
                            const float* __restrict__ W_out,
                            bf16* __restrict__ x_b, bf16* __restrict__ Wih_b,
                            bf16* __restrict__ Whh_i, bf16* __restrict__ Wout_b,
                            bf16* __restrict__ h_slot0, float* __restrict__ c) {
    int tid = blockIdx.x * blockDim.x + threadIdx.x;
    int stride = gridDim.x * blockDim.x;
    for (int i = tid; i < G4 * HDIM; i += stride) {
        int r = i >> 10, k = i & 1023;
        int r2 = ((r & 1023) << 2) | (r >> 10);   // interleave: hcol*4 + gate
        Whh_i[(size_t)r2 * HDIM + k] = (bf16)W_hh[i];
        Wih_b[i] = (bf16)W_ih[i];
    }
    for (int i = tid; i < BATCH * HDIM; i += stride) {
        x_b[i]     = (bf16)x[i];
        Wout_b[i]  = (bf16)W_out[i];
        h_slot0[i] = (bf16)h0[i];
        c[i]       = c0[i];
    }
}

// ---------------- tiled C = A @ B^T + bias(+bias2) (bf16 in, f32 out) ----------------
// 128x128 tile, BK=32, double-buffered LDS via global_load_lds(16B), 4 waves (64x64 each).
// INTER: store columns gate-interleaved (col' = (col&1023)*4 + col>>10).
template <int M, int N, int K, bool INTER>
__global__ __launch_bounds__(256) void gemm_bt_tiled(const bf16* __restrict__ A,
                                                     const bf16* __restrict__ Bw,
                                                     const float* __restrict__ bias,
                                                     const float* __restrict__ bias2,
                                                     float* __restrict__ C) {
    constexpr int MT = M / 128;
    constexpr int NT = N / 128;
    constexpr int TOT = MT * NT;
    __shared__ bf16 sA[2][128 * 32];
    __shared__ bf16 sB[2][128 * 32];

    int bid = blockIdx.x;
    int g = (bid & 7) * (TOT / 8) + (bid >> 3);  // XCD-chunked
    int nt = g % NT, mt = g / NT;
    int mrow0 = mt * 128, ncol0 = nt * 128;

    int tid = threadIdx.x;
    int l = tid & 63;
    int w = tid >> 6;
    int wr = w >> 1, wc = w & 1;
    int lr = l & 15, q = l >> 4;

    const bf16* Abase = A + (size_t)mrow0 * K;
    const bf16* Bbase = Bw + (size_t)ncol0 * K;

    auto stage = [&](const bf16* base, bf16* dst, int k0) {
#pragma unroll
        for (int j = 0; j < 2; ++j) {
            int pbase = w * 64 + 256 * j;
            int p = pbase + l;
            int row = p >> 2, seg = p & 3;
            int sseg = seg ^ swz4(row);
            const bf16* gp = base + (size_t)row * K + k0 + sseg * 8;
            GLOAD_LDS16(gp, dst + pbase * 8);
        }
    };

    stage(Abase, sA[0], 0);
    stage(Bbase, sB[0], 0);
    __syncthreads();

    f32x4 acc[4][4] = {};
    constexpr int NS = K / 32;
    for (int s = 0; s < NS; ++s) {
        int cur = s & 1;
        if (s + 1 < NS) {
            stage(Abase, sA[cur ^ 1], (s + 1) * 32);
            stage(Bbase, sB[cur ^ 1], (s + 1) * 32);
        }
        bf16x8 af[4], bf[4];
#pragma unroll
        for (int fm = 0; fm < 4; ++fm) {
            int row = wr * 64 + fm * 16 + lr;
            af[fm] = *(const bf16x8*)&sA[cur][row * 32 + 8 * (q ^ swz4(row))];
        }
#pragma unroll
        for (int fn = 0; fn < 4; ++fn) {
            int row = wc * 64 + fn * 16 + lr;
            bf[fn] = *(const bf16x8*)&sB[cur][row * 32 + 8 * (q ^ swz4(row))];
        }
#pragma unroll
        for (int fm = 0; fm < 4; ++fm)
#pragma unroll
            for (int fn = 0; fn < 4; ++fn)
                acc[fm][fn] = MFMA16(af[fm], bf[fn], acc[fm][fn]);
        __syncthreads();
    }

#pragma unroll
    for (int fm = 0; fm < 4; ++fm)
#pragma unroll
        for (int fn = 0; fn < 4; ++fn) {
            int col = ncol0 + wc * 64 + fn * 16 + lr;
            float bs = bias[col] + (bias2 ? bias2[col] : 0.0f);
            int colw = INTER ? (((col & 1023) << 2) | (col >> 10)) : col;
#pragma unroll
            for (int r = 0; r < 4; ++r) {
                int row = mrow0 + wr * 64 + fm * 16 + q * 4 + r;
                C[(size_t)row * N + colw] = acc[fm][fn][r] + bs;
            }
        }
}

// ---------------- LSTM step v3: per-launch, L2-hot B stream ----------------
// 256 blocks (1/CU) x 512 threads (8 waves = 4 kw x 2 cw).
// Block tile: 64 batch rows x 128 gatecols (= 32 hcols x 4 gates, interleaved).
// h panel (64x1024, 128 KB) staged once into LDS; K-loop has NO barriers:
// ds_read A-frag + global B-frag (L2-hot, XCD-stable panel) + MFMA.
// Cross-kw reduce through LDS (aliased onto dead A region), fused elementwise epilogue.
__global__ __launch_bounds__(512, 2) void lstm_step3(
    const bf16* __restrict__ h_prev,  // [512][1024] bf16
    const bf16* __restrict__ Whh_i,   // [4096][1024] bf16, rows gate-interleaved
    const float* __restrict__ xWi,    // [512][4096] f32, cols gate-interleaved, biases folded
    float* __restrict__ c,            // [512][1024] f32
    bf16* __restrict__ h_out)         // [512][1024] bf16
{
    __shared__ __align__(16) char smem[131072];    // 128 KB
    bf16*  A_lds = (bf16*)smem;                    // [64 rows][128 slots of 16B]
    float* red   = (float*)smem;                   // alias after K-loop: 6 x 16 KB = 96 KB
    float* gbuf  = (float*)(smem + 98304);         // 32 KB

    int b  = blockIdx.x;
    int nb = ((b & 7) << 2) | ((b >> 3) & 3);      // 0..31 — XCD-stable panel id
    int mb = b >> 5;                               // 0..7

    int tid = threadIdx.x;
    int l   = tid & 63;
    int wid = tid >> 6;        // 0..7
    int kw  = wid >> 1;        // 0..3  K-quarter (256 wide)
    int cw  = wid & 1;         // 0..1  col-half (64 gatecols)
    int lr = l & 15, q = l >> 4;

    int row0 = mb * 64;

    // ---- stage h panel: dest linear, source pre-swizzled (rule #21 pair) ----
    const bf16* hsrc = h_prev + (size_t)row0 * HDIM;
#pragma unroll
    for (int jj = 0; jj < 16; ++jj) {
        int base = jj * 512 + wid * 64;            // wave-uniform 16B-slot base
        int p = base + l;
        int rown = p >> 7, ss = p & 127;
        int sg = ss ^ (rown & 7);
        GLOAD_LDS16(hsrc + (size_t)rown * HDIM + sg * 8, A_lds + (size_t)base * 8);
    }
    __syncthreads();

    // ---- barrier-free K-loop: 8 chunks of K=32 within this wave's quarter ----
    const bf16* Bbase = Whh_i + (size_t)(nb * 128 + cw * 64 + lr) * HDIM + kw * 256 + q * 8;
    f32x4 acc[4][4] = {};
#pragma unroll
    for (int kc = 0; kc < 8; ++kc) {
        bf16x8 bfr[4];
#pragma unroll
        for (int fn = 0; fn < 4; ++fn)
            bfr[fn] = *(const bf16x8*)(Bbase + (size_t)fn * 16 * HDIM + kc * 32);
        bf16x8 afr[4];
#pragma unroll
        for (int fm = 0; fm < 4; ++fm) {
            int rown = fm * 16 + lr;
            int s = kw * 32 + kc * 4 + q;
            afr[fm] = *(const bf16x8*)&A_lds[(size_t)(rown * 128 + (s ^ (rown & 7))) * 8];
        }
#pragma unroll
        for (int fm = 0; fm < 4; ++fm)
#pragma unroll
            for (int fn = 0; fn < 4; ++fn)
                acc[fm][fn] = MFMA16(afr[fm], bfr[fn], acc[fm][fn]);
    }
    __syncthreads();   // everyone done with A_lds -> safe to alias red/gbuf

    // ---- cross-kw reduce (register-exact slot map) ----
    if (kw > 0) {
        float* dst = red + (size_t)((kw - 1) * 2 + cw) * 4096;
#pragma unroll
        for (int fm = 0; fm < 4; ++fm)
#pragma unroll
            for (int fn = 0; fn < 4; ++fn)
#pragma unroll
                for (int r = 0; r < 4; ++r)
                    dst[((fm * 4 + fn) * 4 + r) * 64 + l] = acc[fm][fn][r];
    }
    __syncthreads();
    if (kw == 0) {
#pragma unroll
        for (int fm = 0; fm < 4; ++fm)
#pragma unroll
            for (int fn = 0; fn < 4; ++fn) {
                int col = cw * 64 + fn * 16 + lr;
#pragma unroll
                for (int r = 0; r < 4; ++r) {
                    float v = acc[fm][fn][r];
#pragma unroll
                    for (int j = 0; j < 3; ++j)
                        v += red[(size_t)(j * 2 + cw) * 4096 + ((fm * 4 + fn) * 4 + r) * 64 + l];
                    int row = fm * 16 + q * 4 + r;
                    gbuf[row * 128 + (col ^ ((row & 7) << 2))] = v;   // bank-spread XOR (16B-granular)
                }
            }
    }
    __syncthreads();

    // ---- fused LSTM elementwise: 64 rows x 32 hcols, gates adjacent (float4) ----
#pragma unroll
    for (int it = 0; it < 4; ++it) {
        int idx = it * 512 + tid;
        int row = idx >> 5, hl = idx & 31;
        int grow = row0 + row;
        int hcol = nb * 32 + hl;
        float4 g4 = *(const float4*)&gbuf[row * 128 + ((hl * 4) ^ ((row & 7) << 2))];
        float4 xw = *(const float4*)&xWi[(size_t)grow * G4 + (size_t)hcol * 4];
        float gi = g4.x + xw.x;
        float gf = g4.y + xw.y;
        float gg = g4.z + xw.z;
        float go = g4.w + xw.w;
        size_t cix = (size_t)grow * HDIM + hcol;
        float cn = sigmoid_f(gf) * c[cix] + sigmoid_f(gi) * tanh_f(gg);
        float hn = sigmoid_f(go) * tanh_f(cn);
        c[cix] = cn;
        h_out[cix] = (bf16)hn;
    }
}

// ---------------- launch ----------------
extern "C" void kernel_launch(void* const* d_in, const int* in_sizes, int n_in,
                              void* d_out, int out_size, void* d_ws, size_t ws_size,
                              hipStream_t stream) {
    const float* x    = (const float*)d_in[0];
    const float* h0   = (const float*)d_in[1];
    const float* c0   = (const float*)d_in[2];
    const float* W_ih = (const float*)d_in[3];
    const float* W_hh = (const float*)d_in[4];
    const float* b_ih = (const float*)d_in[5];
    const float* b_hh = (const float*)d_in[6];
    const float* W_out= (const float*)d_in[7];
    const float* b_out= (const float*)d_in[8];

    char* ws = (char*)d_ws;
    bf16*  Whh_i  = (bf16*)(ws + 0);                     // 8 MB (gate-interleaved)
    bf16*  Wih_b  = (bf16*)(ws + (size_t)(8 << 20));     // 8 MB
    bf16*  x_b    = (bf16*)(ws + (size_t)(16 << 20));    // 1 MB
    bf16*  Wout_b = (bf16*)(ws + (size_t)(17 << 20));    // 1 MB
    float* xWbuf  = (float*)(ws + (size_t)(18 << 20));   // 8 MB (interleaved cols, biases folded)
    float* cbuf   = (float*)(ws + (size_t)(26 << 20));   // 2 MB
    bf16*  h_all  = (bf16*)(ws + (size_t)(28 << 20));    // 65 MB (65 slots of 512x1024)

    prep_kernel<<<2048, 256, 0, stream>>>(x, h0, c0, W_ih, W_hh, W_out,
                                          x_b, Wih_b, Whh_i, Wout_b, h_all, cbuf);

    // xWi = x @ W_ih^T + b_ih + b_hh, stored gate-interleaved: M=512, N=4096 -> 128 blocks
    gemm_bt_tiled<BATCH, G4, HDIM, true><<<128, 256, 0, stream>>>(x_b, Wih_b, b_ih, b_hh, xWbuf);

    // 64 LSTM steps, stream-ordered (kernel boundary = cheap global barrier)
    for (int t = 0; t < DSTEP; ++t) {
        lstm_step3<<<256, 512, 0, stream>>>(h_all + (size_t)t * HB, Whh_i, xWbuf,
                                            cbuf, h_all + (size_t)(t + 1) * HB);
    }

    // outs = h_all[1..64] @ W_out^T + b_out : M=32768, N=512 -> 1024 blocks
    gemm_bt_tiled<DSTEP * BATCH, NOUT, HDIM, false><<<1024, 256, 0, stream>>>(
        h_all + HB, Wout_b, b_out, nullptr, (float*)d_out);
}